// Round 12
// baseline (664.189 us; speedup 1.0000x reference)
//
#include <hip/hip_runtime.h>
#include <math.h>

#define U_ 8192
#define I_ 8192
#define D_ 128
#define E_ 524288
#define N_ 16384
#define K_ 32
#define CAP_ 512

typedef unsigned short u16;
typedef unsigned int u32;
typedef unsigned long long u64;
typedef __attribute__((ext_vector_type(8))) short bf16x8;
typedef __attribute__((ext_vector_type(4))) float f32x4;

// ---------------------------------------------------------------- init ------
__global__ void k_init(const float* __restrict__ wq, const float* __restrict__ wk,
                       const float* __restrict__ bq, const float* __restrict__ wv,
                       const float* __restrict__ fw,
                       float* __restrict__ M, float* __restrict__ bqk,
                       float* __restrict__ wvT, float* __restrict__ fwdT,
                       int* __restrict__ cnt, float* __restrict__ cs1,
                       float* __restrict__ cs2,
                       float* __restrict__ svec, int* __restrict__ gcount,
                       int* __restrict__ failn) {
  const int tid = blockIdx.x * 256 + threadIdx.x;   // 64 blocks -> 16384 threads
  cnt[tid] = 0;
  gcount[tid] = 0;
  if (tid < 2048) { cs1[tid] = 0.f; cs2[tid] = 0.f; }   // 16 replicas x 128
  if (tid < 128) svec[tid] = 0.f;
  if (tid == 0) *failn = 0;
  // M[i][j] = sum_l wq[l,i]*wk[l,j]  (wq^T wk)
  const int i = tid >> 7, j = tid & 127;
  float s = 0.f;
  for (int l = 0; l < 128; ++l) s += wq[l * 128 + i] * wk[l * 128 + j];
  M[tid] = s;
  wvT[i * 128 + j] = wv[j * 128 + i];
  fwdT[i * 128 + j] = fw[j * 128 + i];   // fwdT[d][j] = fw[j][d] (d-major)
  if (tid < 128) {
    float s2 = 0.f;
    for (int l = 0; l < 128; ++l) s2 += bq[l] * wk[l * 128 + tid];
    bqk[tid] = s2;
  }
}

// concat (float4) + edge histogram merged: 2048 blocks x 256 = 524288 threads
// = exactly N*D/4 float4 elements = exactly E_ edges (guard-free).
__global__ void k_concat(const float* __restrict__ user, const float* __restrict__ item,
                         float* __restrict__ ego,
                         const int* __restrict__ rows, int* __restrict__ cnt) {
  const int i = blockIdx.x * 256 + threadIdx.x;
  const float4 v = (i < U_ * D_ / 4) ? ((const float4*)user)[i]
                                     : ((const float4*)item)[i - U_ * D_ / 4];
  ((float4*)ego)[i] = v;
  atomicAdd(&cnt[rows[i]], 1);
}

// ------------------------------------------- parallel 3-phase scan ----------
// Replaces the single-block serial scan (one CU, 16 serial chunks) with
// fully parallel phases: per-block sums -> 64-value scan -> local scan+offset.
__global__ void k_scanA(const int* __restrict__ cnt, int* __restrict__ bsum) {
  __shared__ int ws[4];
  const int t = threadIdx.x, lane = t & 63, wid = t >> 6;
  int v = cnt[blockIdx.x * 256 + t];
#pragma unroll
  for (int off = 32; off; off >>= 1) v += __shfl_xor(v, off, 64);
  if (lane == 0) ws[wid] = v;
  __syncthreads();
  if (t == 0) bsum[blockIdx.x] = ws[0] + ws[1] + ws[2] + ws[3];
}

__global__ void k_scanB(const int* __restrict__ bsum, int* __restrict__ boff,
                        int* __restrict__ row_ptr) {
  const int t = threadIdx.x;                // 64 threads, one wave
  const int x = bsum[t];
  int incl = x;
#pragma unroll
  for (int off = 1; off < 64; off <<= 1) {
    const int v = __shfl_up(incl, off, 64);
    if (t >= off) incl += v;
  }
  boff[t] = incl - x;                       // exclusive block offsets
  if (t == 63) row_ptr[N_] = incl;          // grand total
}

__global__ void k_scanC(const int* __restrict__ cnt, const int* __restrict__ boff,
                        int* __restrict__ row_ptr, int* __restrict__ cursor) {
  __shared__ int ws[4];
  const int t = threadIdx.x, lane = t & 63, wid = t >> 6;
  const int g = blockIdx.x * 256 + t;
  const int x = cnt[g];
  int incl = x;
#pragma unroll
  for (int off = 1; off < 64; off <<= 1) {
    const int v = __shfl_up(incl, off, 64);
    if (lane >= off) incl += v;
  }
  if (lane == 63) ws[wid] = incl;
  __syncthreads();
  int wbase = 0;
  for (int k = 0; k < wid; ++k) wbase += ws[k];
  const int excl = boff[blockIdx.x] + wbase + incl - x;
  row_ptr[g] = excl;
  cursor[g] = excl;
}

__global__ void k_scatter(const int* __restrict__ rows, const int* __restrict__ cols,
                          const float* __restrict__ vals, int* __restrict__ cursor,
                          int* __restrict__ ccol, float* __restrict__ cval) {
  const int e = blockIdx.x * 256 + threadIdx.x;
  const int r = rows[e];
  const int p = atomicAdd(&cursor[r], 1);
  ccol[p] = cols[e];
  cval[p] = vals[e];
}

// ---------------------------------------------------------------- SpMM ------
// v4: scalar peel to 4-alignment, then int4/float4 index+value loads with 8
// independent double accumulators; `last` folds the /3.
__global__ __launch_bounds__(128) void k_spmm(const float* __restrict__ x,
                                              float* __restrict__ y,
                                              float* __restrict__ sum,
                                              const int* __restrict__ row_ptr,
                                              const int* __restrict__ ccol,
                                              const float* __restrict__ cval,
                                              const int first, const int last) {
  const int r = blockIdx.x, d = threadIdx.x;
  const int b = row_ptr[r], e = row_ptr[r + 1];
  double a[8];
#pragma unroll
  for (int u = 0; u < 8; ++u) a[u] = 0.0;
  int i = b;
  for (; i < e && (i & 3); ++i)
    a[0] += (double)cval[i] * (double)x[ccol[i] * 128 + d];
  for (; i + 7 < e; i += 8) {
    const int4 ca = *(const int4*)&ccol[i];
    const int4 cb = *(const int4*)&ccol[i + 4];
    const float4 va = *(const float4*)&cval[i];
    const float4 vb = *(const float4*)&cval[i + 4];
    a[0] += (double)va.x * (double)x[ca.x * 128 + d];
    a[1] += (double)va.y * (double)x[ca.y * 128 + d];
    a[2] += (double)va.z * (double)x[ca.z * 128 + d];
    a[3] += (double)va.w * (double)x[ca.w * 128 + d];
    a[4] += (double)vb.x * (double)x[cb.x * 128 + d];
    a[5] += (double)vb.y * (double)x[cb.y * 128 + d];
    a[6] += (double)vb.z * (double)x[cb.z * 128 + d];
    a[7] += (double)vb.w * (double)x[cb.w * 128 + d];
  }
  for (; i < e; ++i)
    a[0] += (double)cval[i] * (double)x[ccol[i] * 128 + d];
  const float f = (float)((((a[0] + a[1]) + (a[2] + a[3])) + ((a[4] + a[5]) + (a[6] + a[7]))));
  y[r * 128 + d] = f;
  float s = first ? f : sum[r * 128 + d] + f;
  if (last) s = s / 3.0f;
  sum[r * 128 + d] = s;
}

// ------------------------------------------------- split + transpose --------
__global__ __launch_bounds__(256) void k_split_t(const float* __restrict__ x,
                                                 u16* __restrict__ Gh, u16* __restrict__ Gl,
                                                 u16* __restrict__ XTh, u16* __restrict__ XTl,
                                                 float* __restrict__ svec) {
  __shared__ u16 lh[128 * 66];
  __shared__ u16 ll[128 * 66];
  const int tid = threadIdx.x;
  const int r0 = blockIdx.x * 64;
  float colsum = 0.f;
  for (int s = 0; s < 32; ++s) {
    const int idx = tid + s * 256;
    const int r = idx >> 7, d = idx & 127;
    const float v = x[(r0 + r) * 128 + d];
    colsum += v;
    unsigned int u = __float_as_uint(v);
    u += 0x7fffu + ((u >> 16) & 1u);
    const u16 h = (u16)(u >> 16);
    const float hf = __uint_as_float(((unsigned int)h) << 16);
    const float l = v - hf;
    unsigned int u2 = __float_as_uint(l);
    u2 += 0x7fffu + ((u2 >> 16) & 1u);
    const u16 lo = (u16)(u2 >> 16);
    Gh[(r0 + r) * 128 + d] = h;
    Gl[(r0 + r) * 128 + d] = lo;
    lh[d * 66 + r] = h;
    ll[d * 66 + r] = lo;
  }
  atomicAdd(&svec[tid & 127], colsum);
  __syncthreads();
  for (int s = 0; s < 32; ++s) {
    const int idx = tid + s * 256;
    const int d = idx >> 6, rr = idx & 63;
    XTh[d * 16384 + r0 + rr] = lh[d * 66 + rr];
    XTl[d * 16384 + r0 + rr] = ll[d * 66 + rr];
  }
}

// ---------------------------------------------------------------- C2 --------
__global__ __launch_bounds__(256) void k_c2mfma(const u16* __restrict__ XTh,
                                                const u16* __restrict__ XTl,
                                                float* __restrict__ C2part) {
  const int tid = threadIdx.x, w = tid >> 6, lane = tid & 63;
  const int n16 = lane & 15, kq = lane >> 4;
  const int c0 = blockIdx.x * 64;
  f32x4 acc[2][8];
#pragma unroll
  for (int a = 0; a < 2; ++a)
#pragma unroll
    for (int b = 0; b < 8; ++b) acc[a][b] = (f32x4){0.f, 0.f, 0.f, 0.f};
  for (int ks = 0; ks < 2; ++ks) {
    const int c = c0 + ks * 32 + kq * 8;
    bf16x8 Fh[8], Fl[8];
#pragma unroll
    for (int g = 0; g < 8; ++g) {
      const int base = (g * 16 + n16) * 16384 + c;
      Fh[g] = *(const bf16x8*)&XTh[base];
      Fl[g] = *(const bf16x8*)&XTl[base];
    }
#pragma unroll
    for (int a = 0; a < 2; ++a) {
      const int tr = w * 2 + a;
#pragma unroll
      for (int b = 0; b < 8; ++b) {
        acc[a][b] = __builtin_amdgcn_mfma_f32_16x16x32_bf16(Fl[tr], Fh[b], acc[a][b], 0, 0, 0);
        acc[a][b] = __builtin_amdgcn_mfma_f32_16x16x32_bf16(Fh[tr], Fl[b], acc[a][b], 0, 0, 0);
        acc[a][b] = __builtin_amdgcn_mfma_f32_16x16x32_bf16(Fh[tr], Fh[b], acc[a][b], 0, 0, 0);
      }
    }
  }
  float* dst = C2part + (size_t)blockIdx.x * 16384;
#pragma unroll
  for (int a = 0; a < 2; ++a) {
    const int tr = w * 2 + a;
#pragma unroll
    for (int b = 0; b < 8; ++b)
#pragma unroll
      for (int i = 0; i < 4; ++i)
        dst[(tr * 16 + kq * 4 + i) * 128 + b * 16 + n16] = acc[a][b][i];
  }
}

// v2: 4 independent accumulators (4 slab loads in flight).
__global__ void k_c2red(const float* __restrict__ C2part, float* __restrict__ C2) {
  const int e = blockIdx.x * 256 + threadIdx.x;   // 64 blocks -> 16384
  float s0 = 0.f, s1 = 0.f, s2 = 0.f, s3 = 0.f;
  for (int b = 0; b < 256; b += 4) {
    s0 += C2part[(size_t)(b + 0) * 16384 + e];
    s1 += C2part[(size_t)(b + 1) * 16384 + e];
    s2 += C2part[(size_t)(b + 2) * 16384 + e];
    s3 += C2part[(size_t)(b + 3) * 16384 + e];
  }
  C2[e] = (s0 + s1) + (s2 + s3);
}

// ------------------------------------------------- qk + tau fused -----------
// Stage the 8 ego rows ONCE; phase 1 = qk thin-tile matmul (identical to
// k_qk v2); phase 2 = tau with the k2 loop split across thread-halves
// (partials additive over the 256-thread reduction; svec term contributed
// by half 0 only).  Saves a launch + an 8MB ego re-read/restage.  Tau
// reassociation ~1e-16 rel -- containment is structural.
__global__ __launch_bounds__(256) void k_qktau(const float* __restrict__ ego,
                                               const float* __restrict__ M,
                                               const float* __restrict__ bqk,
                                               const float* __restrict__ C2,
                                               const float* __restrict__ svec,
                                               float* __restrict__ qkout,
                                               float* __restrict__ tau) {
  __shared__ float xs[8][128];
  __shared__ double r1[8][4], r2[8][4];
  const int tid = threadIdx.x;
  const int r0 = blockIdx.x * 8;
#pragma unroll
  for (int s = 0; s < 4; ++s) {
    const int idx = tid + s * 256;
    xs[idx >> 7][idx & 127] = ego[r0 * 128 + idx];
  }
  __syncthreads();
  const int j = tid & 127, h = tid >> 7;
  // ---- phase 1: qk ----
  {
    const float bj = bqk[j];
    float acc[4];
#pragma unroll
    for (int r = 0; r < 4; ++r) acc[r] = bj;
    for (int d = 0; d < 128; d += 4) {
      const float w0 = M[(d + 0) * 128 + j];
      const float w1 = M[(d + 1) * 128 + j];
      const float w2 = M[(d + 2) * 128 + j];
      const float w3 = M[(d + 3) * 128 + j];
#pragma unroll
      for (int r = 0; r < 4; ++r) {
        const float4 xv = *(const float4*)&xs[h * 4 + r][d];
        acc[r] += xv.x * w0 + xv.y * w1 + xv.z * w2 + xv.w * w3;
      }
    }
#pragma unroll
    for (int r = 0; r < 4; ++r)
      qkout[(r0 + h * 4 + r) * 128 + j] = acc[r];
  }
  // ---- phase 2: tau ----
  const int lane = tid & 63, wid = tid >> 6;
  double y[8];
#pragma unroll
  for (int rr = 0; rr < 8; ++rr) y[rr] = 0.0;
  const int k0 = h * 64;
  for (int k2 = k0; k2 < k0 + 64; ++k2) {
    const double c = (double)C2[k2 * 128 + j];
#pragma unroll
    for (int rr = 0; rr < 8; ++rr) y[rr] += (double)xs[rr][k2] * c;
  }
  const double sv = (h == 0) ? (double)svec[j] : 0.0;
#pragma unroll
  for (int rr = 0; rr < 8; ++rr) {
    double v1 = (double)xs[rr][j] * y[rr];
    double v2 = (double)xs[rr][j] * sv;
#pragma unroll
    for (int off = 32; off; off >>= 1) {
      v1 += __shfl_xor(v1, off, 64);
      v2 += __shfl_xor(v2, off, 64);
    }
    if (lane == 0) { r1[rr][wid] = v1; r2[rr][wid] = v2; }
  }
  __syncthreads();
  if (tid < 8) {
    const double exy = (r1[tid][0] + r1[tid][1] + r1[tid][2] + r1[tid][3]) / 16384.0;
    const double m = (r2[tid][0] + r2[tid][1] + r2[tid][2] + r2[tid][3]) / 16384.0;
    double var = exy - m * m;
    if (var < 0.0) var = 0.0;
    tau[r0 + tid] = (float)(m + 2.55 * sqrt(var));
  }
}

// ------------------------------------------------------- sim via MFMA -------
// Round-8 winner, untouched (protected): round-6 cfg + swizzled gload_lds.
__device__ __forceinline__ void gload_lds16(const u16* g, u16* l) {
  __builtin_amdgcn_global_load_lds(
      (const __attribute__((address_space(1))) void*)g,
      (__attribute__((address_space(3))) void*)l, 16, 0, 0);
}

__global__ __launch_bounds__(256) void k_simmfma(const u16* __restrict__ Gh,
                                                 const u16* __restrict__ Gl,
                                                 const float* __restrict__ tau,
                                                 int* __restrict__ gstripcnt,
                                                 int2* __restrict__ gbuf) {
  __shared__ __align__(16) u16 lh[64 * 128];   // 16 KB, linear 256-B rows
  __shared__ int cnt128[128];
  const int tid = threadIdx.x;
  const int w = tid >> 6, lane = tid & 63;
  const int strip = blockIdx.x & 15, rgrp = blockIdx.x >> 4;
  const int n16 = lane & 15, kq = lane >> 4;

  if (tid < 128) cnt128[tid] = 0;

  const int rowbase = rgrp * 128 + w * 32;
  bf16x8 Bh[2][4], Bl[2][4];
#pragma unroll
  for (int rg = 0; rg < 2; ++rg) {
    const int row = rowbase + rg * 16 + n16;
#pragma unroll
    for (int q = 0; q < 4; ++q) {
      Bh[rg][q] = *(const bf16x8*)&Gh[row * 128 + q * 32 + kq * 8];
      Bl[rg][q] = *(const bf16x8*)&Gl[row * 128 + q * 32 + kq * 8];
    }
  }
  const float tau0 = tau[rowbase + n16];
  const float tau1 = tau[rowbase + 16 + n16];
  const int col0 = strip * 1024;

  for (int st = 0; st < 16; ++st) {
    const int cb = col0 + st * 64;
    __syncthreads();
#pragma unroll
    for (int ii = 0; ii < 4; ++ii) {
      const int srow = w * 16 + ii * 4 + kq;
      const int chunk = n16 ^ (srow & 7);
      gload_lds16(Gh + (((size_t)(cb + srow)) << 7) + chunk * 8,
                  lh + ((w * 16 + ii * 4) << 7));
    }
    __syncthreads();   // drains vmcnt: staged tile visible to all waves
#pragma unroll
    for (int ct = 0; ct < 4; ++ct) {
      const int ar = ct * 16 + n16;
      const char* lbase = (const char*)lh + ar * 256;
      bf16x8 Ah[4];
#pragma unroll
      for (int q = 0; q < 4; ++q)
        Ah[q] = *(const bf16x8*)(lbase + ((q * 64 + kq * 16) ^ ((ar & 7) << 4)));
#pragma unroll
      for (int rg = 0; rg < 2; ++rg) {
        f32x4 p = {0.f, 0.f, 0.f, 0.f};
        f32x4 r = {0.f, 0.f, 0.f, 0.f};
#pragma unroll
        for (int q = 0; q < 4; ++q) {
          p = __builtin_amdgcn_mfma_f32_16x16x32_bf16(Ah[q], Bh[rg][q], p, 0, 0, 0);
          r = __builtin_amdgcn_mfma_f32_16x16x32_bf16(Ah[q], Bl[rg][q], r, 0, 0, 0);
        }
        const float tv = rg ? tau1 : tau0;
        const int lrow = w * 32 + rg * 16 + n16;     // block-local row 0..127
        const int row = rgrp * 128 + lrow;
#pragma unroll
        for (int i = 0; i < 4; ++i) {
          const float v = p[i] + r[i];
          if (v > tv) {
            const int c = cb + ct * 16 + kq * 4 + i;
            const int pos = atomicAdd(&cnt128[lrow], 1);   // LDS atomic
            if (pos < 32)
              gbuf[row * CAP_ + strip * 32 + pos] = make_int2(c, __float_as_int(v));
          }
        }
      }
    }
  }
  __syncthreads();
  if (tid < 128) gstripcnt[(rgrp * 128 + tid) * 16 + strip] = cnt128[tid];
}

// Top-32 by stored fp32 sim values via RANK-SCATTER on packed u64 keys.
// Also performs the count check; bad rows pushed to failq by lane 0.
__global__ __launch_bounds__(256) void k_refine(const int* __restrict__ gstripcnt,
                                                const int2* __restrict__ gbuf,
                                                int* __restrict__ topk_idx,
                                                int* __restrict__ failq,
                                                int* __restrict__ failn) {
  __shared__ u64 lk[4][CAP_];
  const int tid = threadIdx.x, w = tid >> 6, lane = tid & 63;
  const int n = blockIdx.x * 4 + w;

  const int scn = (lane < 16) ? gstripcnt[n * 16 + lane] : 0;
  int total = 0, over = 0;
#pragma unroll
  for (int s = 0; s < 16; ++s) {
    const int c = __shfl(scn, s, 64);
    total += c;
    over |= (c > 32);
  }
  const int bad = (total < 36 || total > CAP_ || over);
  const int cnt = bad ? 0 : total;

  // compact the 16 segments into lk[w][0..cnt)
  int base = 0;
#pragma unroll
  for (int s = 0; s < 16; ++s) {
    const int c = __shfl(scn, s, 64);
    if (!bad && lane < c) {
      const int2 p = gbuf[n * CAP_ + s * 32 + lane];
      u32 uv = (u32)p.y;
      uv = (uv >> 31) ? ~uv : (uv | 0x80000000u);
      lk[w][base + lane] = ((u64)uv << 32) | (u64)(16383 - p.x);
    }
    base += bad ? 0 : c;
  }
  __syncthreads();

  for (int ci = lane; ci < cnt; ci += 64) {
    const u64 kk = lk[w][ci];
    int r = 0;
#pragma unroll 4
    for (int j = 0; j < cnt; ++j)
      r += (lk[w][j] > kk) ? 1 : 0;
    if (r < 32) topk_idx[n * 32 + r] = 16383 - (int)(u32)(kk & 0xffffffffu);
  }
  if (bad) {
    if (lane == 0) {
      const int s = atomicAdd(failn, 1);
      if (s < 64) failq[s] = n;
    }
    if (lane < 32) topk_idx[n * 32 + lane] = 0;  // placeholder; fallback overwrites
  }
}

// exact fp64 full-row top-32 for statistically-failed rows (expected: none)
__global__ __launch_bounds__(256) void k_fallback(const float* __restrict__ x,
                                                  const int* __restrict__ failq,
                                                  const int* __restrict__ failn,
                                                  double* __restrict__ fsim,
                                                  int* __restrict__ topk_idx) {
  const int nf = *failn;
  const int which = blockIdx.x;
  if (which >= nf || which >= 64) return;
  const int row = failq[which];
  __shared__ float xs[128];
  __shared__ double bm[256];
  __shared__ int bc[256];
  const int tid = threadIdx.x;
  if (tid < 128) xs[tid] = x[row * 128 + tid];
  __syncthreads();
  double* fs = fsim + (size_t)which * 16384;
  for (int c = tid; c < 16384; c += 256) {
    const float4* xp = (const float4*)&x[c * 128];
    double a = 0.0;
    for (int d = 0; d < 32; ++d) {
      const float4 v = xp[d];
      a += (double)xs[d * 4 + 0] * (double)v.x + (double)xs[d * 4 + 1] * (double)v.y +
           (double)xs[d * 4 + 2] * (double)v.z + (double)xs[d * 4 + 3] * (double)v.w;
    }
    fs[c] = a;
  }
  __syncthreads();
  for (int r = 0; r < 32; ++r) {
    double m = -1.0e300; int mc = 0;
    for (int c = tid; c < 16384; c += 256) {
      const double v = fs[c];
      if (v > m || (v == m && c < mc)) { m = v; mc = c; }
    }
    bm[tid] = m; bc[tid] = mc;
    __syncthreads();
    for (int s = 128; s; s >>= 1) {
      if (tid < s) {
        if (bm[tid + s] > bm[tid] || (bm[tid + s] == bm[tid] && bc[tid + s] < bc[tid])) {
          bm[tid] = bm[tid + s]; bc[tid] = bc[tid + s];
        }
      }
      __syncthreads();
    }
    if (tid == 0) { topk_idx[row * 32 + r] = bc[0]; fs[bc[0]] = -1.0e300; }
    __syncthreads();
  }
}

// ------------------------------------------------------- attention ----------
// v3: 256 threads/node; float2 gather; split score/PV phases.
__global__ __launch_bounds__(256) void k_attn(const float* __restrict__ ego,
                                              float* __restrict__ qk,
                                              const int* __restrict__ topk_idx) {
  __shared__ float qv[128];
  __shared__ float sm[32 * 130];
  __shared__ int tki[32];
  __shared__ float sc[32];
  __shared__ float psum[256];
  const int n = blockIdx.x, tid = threadIdx.x;
  if (tid < 128) qv[tid] = qk[n * 128 + tid];
  if (tid < 32) tki[tid] = topk_idx[n * 32 + tid] & 16383;
  __syncthreads();
  for (int e = tid; e < 2048; e += 256) {
    const int k2 = e >> 6, d2 = e & 63;
    const float2 v = *(const float2*)&ego[(size_t)tki[k2] * 128 + d2 * 2];
    *(float2*)&sm[k2 * 130 + d2 * 2] = v;
  }
  __syncthreads();
  {
    const int kk = tid & 31, part = tid >> 5;    // 8 parts x 16 d each
    float s = 0.f;
    const int d0 = part * 16;
    for (int d = d0; d < d0 + 16; ++d) s += qv[d] * sm[kk * 130 + d];
    psum[tid] = s;
  }
  __syncthreads();
  if (tid < 32) {
    float v = 0.f;
#pragma unroll
    for (int p = 0; p < 8; ++p) v += psum[tid + p * 32];
    v *= (1.0f / 11.313708498984760f);    // 1/sqrt(128)
    float m = v;
#pragma unroll
    for (int off = 16; off; off >>= 1) m = fmaxf(m, __shfl_xor(m, off, 32));
    const float e = expf(v - m);
    float ssum = e;
#pragma unroll
    for (int off = 16; off; off >>= 1) ssum += __shfl_xor(ssum, off, 32);
    sc[tid] = e / ssum;
  }
  __syncthreads();
  {
    const int d = tid & 127, half = tid >> 7;    // 2 halves x 16 k each
    float s = 0.f;
    const int k0 = half * 16;
    for (int k2 = k0; k2 < k0 + 16; ++k2) s += sc[k2] * sm[k2 * 130 + d];
    psum[tid] = s;
  }
  __syncthreads();
  if (tid < 128) qk[n * 128 + tid] = psum[tid] + psum[tid + 128];
}

// ------------------------------------------- attnmm + fuse1 fused -----------
__global__ __launch_bounds__(256) void k_attnfuse(const float* __restrict__ sa,
                                                  const float* __restrict__ ego,
                                                  const float* __restrict__ allemb,
                                                  const float* __restrict__ wvT,
                                                  const float* __restrict__ bv,
                                                  const float* __restrict__ fwdT,
                                                  const float* __restrict__ fb,
                                                  float* __restrict__ atten,
                                                  float* __restrict__ z1,
                                                  float* __restrict__ z2,
                                                  float* __restrict__ cs1,
                                                  float* __restrict__ cs2) {
  __shared__ float xs[8][128];    // sa rows
  __shared__ float xa[8][128];    // allemb rows
  __shared__ float as_[8][128];   // atten rows (computed)
  __shared__ float red1[2][128];
  __shared__ float red2[2][128];
  const int tid = threadIdx.x;
  const int r0 = blockIdx.x * 8;
#pragma unroll
  for (int s = 0; s < 4; ++s) {
    const int idx = tid + s * 256;
    const int rr = idx >> 7, d = idx & 127;
    xs[rr][d] = sa[(r0 + rr) * 128 + d];
    xa[rr][d] = allemb[(r0 + rr) * 128 + d];
  }
  __syncthreads();
  const int j = tid & 127, h = tid >> 7;
  // phase 1: projection
  {
    const float bj = bv[j];
    float acc[4];
#pragma unroll
    for (int r = 0; r < 4; ++r) acc[r] = bj;
    for (int d = 0; d < 128; d += 4) {
      const float w0 = wvT[(d + 0) * 128 + j];
      const float w1 = wvT[(d + 1) * 128 + j];
      const float w2 = wvT[(d + 2) * 128 + j];
      const float w3 = wvT[(d + 3) * 128 + j];
#pragma unroll
      for (int r = 0; r < 4; ++r) {
        const float4 xv = *(const float4*)&xs[h * 4 + r][d];
        acc[r] += xv.x * w0 + xv.y * w1 + xv.z * w2 + xv.w * w3;
      }
    }
#pragma unroll
    for (int r = 0; r < 4; ++r) {
      const int n = r0 + h * 4 + r;
      const float av = acc[r] + 0.1f * ego[n * 128 + j];
      atten[n * 128 + j] = av;
      as_[h * 4 + r][j] = av;
    }
  }
  __syncthreads();
  // phase 2: fuse gating
  const float fbj = fb[j];
  float acc1[4], acc2[4];
#pragma unroll
  for (int r = 0; r < 4; ++r) { acc1[r] = fbj; acc2[r] = fbj; }
  for (int d = 0; d < 128; d += 4) {
    const float w0 = fwdT[(d + 0) * 128 + j];
    const float w1 = fwdT[(d + 1) * 128 + j];
    const float w2 = fwdT[(d + 2) * 128 + j];
    const float w3 = fwdT[(d + 3) * 128 + j];
#pragma unroll
    for (int r = 0; r < 4; ++r) {
      const int rr = h * 4 + r;
      const float4 xv = *(const float4*)&xa[rr][d];
      const float4 av = *(const float4*)&as_[rr][d];
      acc1[r] += xv.x * w0 + xv.y * w1 + xv.z * w2 + xv.w * w3;
      acc2[r] += av.x * w0 + av.y * w1 + av.z * w2 + av.w * w3;
    }
  }
  float ls1 = 0.f, ls2 = 0.f;
#pragma unroll
  for (int r = 0; r < 4; ++r) {
    const int rr = h * 4 + r;
    const float t1 = tanhf(acc1[r]);
    const float t2 = tanhf(acc2[r]);
    z1[(r0 + rr) * 128 + j] = t1;
    z2[(r0 + rr) * 128 + j] = t2;
    ls1 += expf(t1 - 1.0f);
    ls2 += expf(t2 - 1.0f);
  }
  red1[h][j] = ls1;
  red2[h][j] = ls2;
  __syncthreads();
  if (h == 0) {
    const int rep = blockIdx.x & 15;
    atomicAdd(&cs1[rep * 128 + j], red1[0][j] + red1[1][j]);
    atomicAdd(&cs2[rep * 128 + j], red2[0][j] + red2[1][j]);
  }
}

// float4 body; 2048 blocks x 256.
__global__ void k_fuse2(const float* __restrict__ allemb, const float* __restrict__ atten,
                        const float* __restrict__ z1, const float* __restrict__ z2,
                        const float* __restrict__ cs1, const float* __restrict__ cs2,
                        float* __restrict__ fusion) {
  __shared__ float s1[128], s2[128];
  const int tid = threadIdx.x;
  if (tid < 128) {
    float a = 0.f, b = 0.f;
#pragma unroll
    for (int rep = 0; rep < 16; ++rep) {
      a += cs1[rep * 128 + tid];
      b += cs2[rep * 128 + tid];
    }
    s1[tid] = a; s2[tid] = b;
  }
  __syncthreads();
  const int i = blockIdx.x * 256 + tid;          // float4 index, 524288 total
  const int j0 = (i & 31) * 4;
  const float4 zv1 = ((const float4*)z1)[i];
  const float4 zv2 = ((const float4*)z2)[i];
  const float4 xv = ((const float4*)allemb)[i];
  const float4 av = ((const float4*)atten)[i];
  float4 o;
  o.x = expf(zv1.x - 1.0f) / s1[j0 + 0] * xv.x + expf(zv2.x - 1.0f) / s2[j0 + 0] * av.x;
  o.y = expf(zv1.y - 1.0f) / s1[j0 + 1] * xv.y + expf(zv2.y - 1.0f) / s2[j0 + 1] * av.y;
  o.z = expf(zv1.z - 1.0f) / s1[j0 + 2] * xv.z + expf(zv2.z - 1.0f) / s2[j0 + 2] * av.z;
  o.w = expf(zv1.w - 1.0f) / s1[j0 + 3] * xv.w + expf(zv2.w - 1.0f) / s2[j0 + 3] * av.w;
  ((float4*)fusion)[i] = o;
}

// ---------------------------------------------------------------- launch ----
extern "C" void kernel_launch(void* const* d_in, const int* in_sizes, int n_in,
                              void* d_out, int out_size, void* d_ws, size_t ws_size,
                              hipStream_t stream) {
  (void)in_sizes; (void)n_in; (void)out_size; (void)ws_size;
  const float* user = (const float*)d_in[0];
  const float* item = (const float*)d_in[1];
  const int* adj_rows = (const int*)d_in[2];
  const int* adj_cols = (const int*)d_in[3];
  const float* adj_vals = (const float*)d_in[4];
  const float* wq = (const float*)d_in[5];
  const float* bq = (const float*)d_in[6];
  const float* wk = (const float*)d_in[7];
  const float* wv = (const float*)d_in[9];
  const float* bv = (const float*)d_in[10];
  const float* fw = (const float*)d_in[11];
  const float* fb = (const float*)d_in[12];

  float* out = (float*)d_out;
  float* allemb = out;                    // [N,D]
  float* atten = out + (size_t)N_ * D_;   // [N,D]
  float* fusion = out + (size_t)2 * N_ * D_;

  char* ws = (char*)d_ws;
  size_t off = 0;
  auto alloc = [&](size_t bytes) { char* p = ws + off; off += (bytes + 255) & ~(size_t)255; return p; };
  float* ego_a = (float*)alloc((size_t)N_ * D_ * 4);
  float* ego_b = (float*)alloc((size_t)N_ * D_ * 4);
  float* qkbuf = (float*)alloc((size_t)N_ * D_ * 4);
  u16* Gh = (u16*)alloc((size_t)N_ * D_ * 2);
  u16* Gl = (u16*)alloc((size_t)N_ * D_ * 2);
  u16* XTh = (u16*)alloc((size_t)N_ * D_ * 2);
  u16* XTl = (u16*)alloc((size_t)N_ * D_ * 2);
  int2* gbuf = (int2*)alloc((size_t)N_ * CAP_ * 8);  // (col,val) pairs (aliased by z1)
  float* z1 = (float*)gbuf;                          // lifetimes disjoint
  float* z2 = (float*)alloc((size_t)N_ * D_ * 4);
  int* topk_idx = (int*)alloc((size_t)N_ * 32 * 4);
  int* ccol = (int*)alloc((size_t)E_ * 4);
  float* cval = (float*)alloc((size_t)E_ * 4);
  int* cnt = (int*)alloc((size_t)N_ * 4);
  int* row_ptr = (int*)alloc((size_t)(N_ + 1) * 4);
  int* cursor = (int*)alloc((size_t)N_ * 4);
  int* bsum = (int*)alloc(64 * 4);
  int* boff = (int*)alloc(64 * 4);
  float* M = (float*)alloc(128 * 128 * 4);
  float* bqk = (float*)alloc(128 * 4);
  float* wvT = (float*)alloc(128 * 128 * 4);
  float* fwdT = (float*)alloc(128 * 128 * 4);
  float* cs1 = (float*)alloc(16 * 128 * 4);           // 16 replicas
  float* cs2 = (float*)alloc(16 * 128 * 4);
  float* C2 = (float*)alloc(128 * 128 * 4);
  float* C2part = (float*)alloc((size_t)256 * 16384 * 4);   // 16 MB partials
  float* svec = (float*)alloc(128 * 4);
  float* tau = (float*)alloc((size_t)N_ * 4);
  int* gcount = (int*)alloc((size_t)N_ * 4);          // legacy (unused by hot path)
  int* gstripcnt = (int*)alloc((size_t)N_ * 16 * 4);  // per (row,strip) counts
  int* failq = (int*)alloc(64 * 4);
  int* failn = (int*)alloc(4);
  double* fsim = (double*)alloc((size_t)64 * N_ * 8);

  k_init<<<64, 256, 0, stream>>>(wq, wk, bq, wv, fw, M, bqk, wvT, fwdT, cnt, cs1, cs2, svec, gcount, failn);
  k_concat<<<2048, 256, 0, stream>>>(user, item, ego_a, adj_rows, cnt);   // float4 + hist
  k_scanA<<<64, 256, 0, stream>>>(cnt, bsum);
  k_scanB<<<1, 64, 0, stream>>>(bsum, boff, row_ptr);
  k_scanC<<<64, 256, 0, stream>>>(cnt, boff, row_ptr, cursor);
  k_scatter<<<2048, 256, 0, stream>>>(adj_rows, adj_cols, adj_vals, cursor, ccol, cval);

  k_spmm<<<N_, 128, 0, stream>>>(ego_a, ego_b, allemb, row_ptr, ccol, cval, 1, 0);
  k_spmm<<<N_, 128, 0, stream>>>(ego_b, ego_a, allemb, row_ptr, ccol, cval, 0, 0);
  k_spmm<<<N_, 128, 0, stream>>>(ego_a, ego_b, allemb, row_ptr, ccol, cval, 0, 1);
  // ego3 = ego_b; allemb = mean of layers (div folded into last pass)

  k_split_t<<<256, 256, 0, stream>>>(ego_b, Gh, Gl, XTh, XTl, svec);
  k_c2mfma<<<256, 256, 0, stream>>>(XTh, XTl, C2part);
  k_c2red<<<64, 256, 0, stream>>>(C2part, C2);
  k_qktau<<<2048, 256, 0, stream>>>(ego_b, M, bqk, C2, svec, qkbuf, tau);  // qk+tau fused

  k_simmfma<<<2048, 256, 0, stream>>>(Gh, Gl, tau, gstripcnt, gbuf);
  k_refine<<<4096, 256, 0, stream>>>(gstripcnt, gbuf, topk_idx, failq, failn);
  k_fallback<<<64, 256, 0, stream>>>(ego_b, failq, failn, fsim, topk_idx);
  k_attn<<<N_, 256, 0, stream>>>(ego_b, qkbuf, topk_idx);          // -> sa in qkbuf
  k_attnfuse<<<2048, 256, 0, stream>>>(qkbuf, ego_b, allemb, wvT, bv, fwdT, fb,
                                       atten, z1, z2, cs1, cs2);
  k_fuse2<<<2048, 256, 0, stream>>>(allemb, atten, z1, z2, cs1, cs2, fusion);
}